// Round 1
// baseline (1009.469 us; speedup 1.0000x reference)
//
#include <hip/hip_runtime.h>
#include <math.h>

// Problem constants
#define BTN   65536          // BT*N rows
#define D_    256
#define NE    512
#define NNODE 64
#define NHEAD 4
#define SLOPE 0.2f

// ---------------------------------------------------------------------------
// CSR build (by src) + per-edge log(A0[src,dst]+eps). Trivial single-thread.
// ---------------------------------------------------------------------------
__global__ void build_csr(const int* __restrict__ src, const int* __restrict__ dst,
                          const float* __restrict__ A0,
                          int* __restrict__ csr_off, int* __restrict__ csr_eid,
                          float* __restrict__ logA0)
{
    if (threadIdx.x != 0 || blockIdx.x != 0) return;
    int cnt[NNODE];
    for (int n = 0; n < NNODE; ++n) cnt[n] = 0;
    for (int e = 0; e < NE; ++e) cnt[src[e]]++;
    int off = 0;
    for (int n = 0; n < NNODE; ++n) { csr_off[n] = off; off += cnt[n]; cnt[n] = csr_off[n]; }
    csr_off[NNODE] = off;
    for (int e = 0; e < NE; ++e) {
        csr_eid[cnt[src[e]]++] = e;
        logA0[e] = logf(A0[src[e] * NNODE + dst[e]] + 1e-8f);
    }
}

// ---------------------------------------------------------------------------
// fp32 GEMM  C[m][j] = sum_k A[m][k] * W[j][k]   (C = A * W^T), K = N = 256
// 64x64 tile, BK=32, 256 threads, 4x4 per thread.
// ---------------------------------------------------------------------------
__global__ __launch_bounds__(256) void gemm_nt(const float* __restrict__ A,
                                               const float* __restrict__ W,
                                               float* __restrict__ C)
{
    __shared__ float As[64][33];   // [m][k], +1 pad
    __shared__ float Bs[32][68];   // [k][j], row stride 68 floats = 16B-aligned rows
    const int t  = threadIdx.x;
    const int tx = t & 15, ty = t >> 4;
    const int m0 = blockIdx.x * 64;
    const int n0 = blockIdx.y * 64;

    float acc[4][4] = {};

    for (int k0 = 0; k0 < D_; k0 += 32) {
        // stage A tile 64x32 (2 float4 per thread, coalesced over k)
        int idx = t;
        #pragma unroll
        for (int r = 0; r < 2; ++r, idx += 256) {
            int row = idx >> 3, cb = (idx & 7) << 2;
            float4 v = *reinterpret_cast<const float4*>(&A[(size_t)(m0 + row) * D_ + k0 + cb]);
            As[row][cb] = v.x; As[row][cb + 1] = v.y; As[row][cb + 2] = v.z; As[row][cb + 3] = v.w;
        }
        // stage B tile: W[n0+j][k0+k] -> Bs[k][j]
        idx = t;
        #pragma unroll
        for (int r = 0; r < 2; ++r, idx += 256) {
            int row = idx >> 3, cb = (idx & 7) << 2;
            float4 v = *reinterpret_cast<const float4*>(&W[(size_t)(n0 + row) * D_ + k0 + cb]);
            Bs[cb][row] = v.x; Bs[cb + 1][row] = v.y; Bs[cb + 2][row] = v.z; Bs[cb + 3][row] = v.w;
        }
        __syncthreads();

        #pragma unroll
        for (int kk = 0; kk < 32; ++kk) {
            float4 b = *reinterpret_cast<const float4*>(&Bs[kk][tx * 4]);
            #pragma unroll
            for (int i = 0; i < 4; ++i) {
                float av = As[ty * 4 + i][kk];
                acc[i][0] += av * b.x;
                acc[i][1] += av * b.y;
                acc[i][2] += av * b.z;
                acc[i][3] += av * b.w;
            }
        }
        __syncthreads();
    }

    #pragma unroll
    for (int i = 0; i < 4; ++i) {
        float4 v = make_float4(acc[i][0], acc[i][1], acc[i][2], acc[i][3]);
        *reinterpret_cast<float4*>(&C[(size_t)(m0 + ty * 4 + i) * D_ + n0 + tx * 4]) = v;
    }
}

// ---------------------------------------------------------------------------
// Edge scores: e[bt][e][h] = sum_d lrelu(Xq[bt,src,h,d]+Xq[bt,dst,h,d])*a[h,d]
//              + log(A0[src,dst]+eps)
// One block per (bt, e); 256 threads = 4 heads x 64 dims; wave-reduce per head.
// ---------------------------------------------------------------------------
__global__ __launch_bounds__(256) void edge_e_kernel(const float* __restrict__ Xq,
    const int* __restrict__ src, const int* __restrict__ dst,
    const float* __restrict__ a, const float* __restrict__ logA0,
    float* __restrict__ ebuf)
{
    const int bid = blockIdx.x;
    const int bt  = bid >> 9;        // / 512
    const int e   = bid & (NE - 1);
    const int t   = threadIdx.x;
    const int s   = src[e], d = dst[e];

    float q = Xq[((size_t)bt * NNODE + s) * D_ + t];
    float k = Xq[((size_t)bt * NNODE + d) * D_ + t];
    float x = q + k;
    x = x > 0.f ? x : SLOPE * x;
    float p = x * a[t];

    #pragma unroll
    for (int o = 32; o > 0; o >>= 1) p += __shfl_xor(p, o, 64);

    if ((t & 63) == 0)
        ebuf[((size_t)bt * NE + e) * NHEAD + (t >> 6)] = p + logA0[e];
}

// ---------------------------------------------------------------------------
// Segment softmax + aggregate:
// Y[bt,n,h,d] = sum_{e in CSR[n]} softmax_e(ebuf) * Xv[bt,dst[e],h,d]
// One block per (bt, n); thread t -> h = t>>6, d = t&63.
// ---------------------------------------------------------------------------
__global__ __launch_bounds__(256) void aggregate_kernel(const float* __restrict__ Xv,
    const float* __restrict__ ebuf, const int* __restrict__ csr_off,
    const int* __restrict__ csr_eid, const int* __restrict__ dst,
    float* __restrict__ Y)
{
    const int bid = blockIdx.x;
    const int bt  = bid >> 6;
    const int n   = bid & (NNODE - 1);
    const int t   = threadIdx.x;
    const int h   = t >> 6;
    const int o0  = csr_off[n], o1 = csr_off[n + 1];
    const size_t yidx = ((size_t)bt * NNODE + n) * D_ + t;

    if (o0 == o1) { Y[yidx] = 0.f; return; }   // empty segment -> zeros (no 0/0)

    float m = -INFINITY;
    for (int i = o0; i < o1; ++i) {
        int eid = csr_eid[i];
        m = fmaxf(m, ebuf[((size_t)bt * NE + eid) * NHEAD + h]);
    }
    float denom = 0.f, acc = 0.f;
    for (int i = o0; i < o1; ++i) {
        int eid = csr_eid[i];
        float w = __expf(ebuf[((size_t)bt * NE + eid) * NHEAD + h] - m);
        denom += w;
        acc   += w * Xv[((size_t)bt * NNODE + dst[eid]) * D_ + t];
    }
    Y[yidx] = acc / denom;
}

// ---------------------------------------------------------------------------
extern "C" void kernel_launch(void* const* d_in, const int* in_sizes, int n_in,
                              void* d_out, int out_size, void* d_ws, size_t ws_size,
                              hipStream_t stream)
{
    const float* H     = (const float*)d_in[0];
    const float* W_lin = (const float*)d_in[1];
    const float* W_val = (const float*)d_in[2];
    const float* a     = (const float*)d_in[3];
    const float* W_out = (const float*)d_in[4];
    const float* A0    = (const float*)d_in[5];
    const int*   src   = (const int*)d_in[6];
    const int*   dst   = (const int*)d_in[7];
    float* out = (float*)d_out;

    const size_t nX = (size_t)BTN * D_;          // 16.7M floats
    const size_t ne = (size_t)1024 * NE * NHEAD; // 2.1M floats
    float* Xq    = (float*)d_ws;
    float* Xv    = Xq + nX;
    float* ebuf  = Xv + nX;
    float* logA0 = ebuf + ne;
    int*   csr_off = (int*)(logA0 + NE);
    int*   csr_eid = csr_off + (NNODE + 1);
    size_t need = (size_t)((char*)(csr_eid + NE) - (char*)d_ws);
    if (ws_size < need) return;  // visible failure rather than OOB writes

    build_csr<<<1, 64, 0, stream>>>(src, dst, A0, csr_off, csr_eid, logA0);

    dim3 gg(BTN / 64, D_ / 64);
    gemm_nt<<<gg, 256, 0, stream>>>(H, W_lin, Xq);
    gemm_nt<<<gg, 256, 0, stream>>>(H, W_val, Xv);

    edge_e_kernel<<<1024 * NE, 256, 0, stream>>>(Xq, src, dst, a, logA0, ebuf);

    float* Y = Xq;  // Xq dead after edge kernel; reuse for Y
    aggregate_kernel<<<1024 * NNODE, 256, 0, stream>>>(Xv, ebuf, csr_off, csr_eid, dst, Y);

    gemm_nt<<<gg, 256, 0, stream>>>(Y, W_out, out);
}

// Round 2
// 619.729 us; speedup vs baseline: 1.6289x; 1.6289x over previous
//
#include <hip/hip_runtime.h>
#include <math.h>

#define BTN   65536          // BT*N rows
#define D_    256
#define NE    512
#define NNODE 64
#define NHEAD 4
#define SLOPE 0.2f

typedef __attribute__((ext_vector_type(4))) float f32x4;
typedef __attribute__((ext_vector_type(8))) short s16x8;

// round-to-nearest-even fp32 -> bf16 (raw bits)
__device__ inline unsigned short f2bf(float x) {
    union { float f; unsigned u; } v; v.f = x;
    unsigned r = v.u + 0x7fff + ((v.u >> 16) & 1);
    return (unsigned short)(r >> 16);
}
__device__ inline float bf2f(unsigned short b) {
    union { float f; unsigned u; } v; v.u = ((unsigned)b) << 16;
    return v.f;
}

// ---------------------------------------------------------------------------
// CSR build (by src) + per-edge log(A0[src,dst]+eps). Trivial single-thread.
// ---------------------------------------------------------------------------
__global__ void build_csr(const int* __restrict__ src, const int* __restrict__ dst,
                          const float* __restrict__ A0,
                          int* __restrict__ csr_off, int* __restrict__ csr_eid,
                          float* __restrict__ logA0)
{
    if (threadIdx.x != 0 || blockIdx.x != 0) return;
    int cnt[NNODE];
    for (int n = 0; n < NNODE; ++n) cnt[n] = 0;
    for (int e = 0; e < NE; ++e) cnt[src[e]]++;
    int off = 0;
    for (int n = 0; n < NNODE; ++n) { csr_off[n] = off; off += cnt[n]; cnt[n] = csr_off[n]; }
    csr_off[NNODE] = off;
    for (int e = 0; e < NE; ++e) {
        csr_eid[cnt[src[e]]++] = e;
        logA0[e] = logf(A0[src[e] * NNODE + dst[e]] + 1e-8f);
    }
}

// ---------------------------------------------------------------------------
// Split-bf16 MFMA GEMM: C[m][n] = sum_k A[m][k] * W[n][k]  (C = A * W^T)
// fp32 in / fp32 out; fp32 values split into bf16 hi+lo during LDS staging;
// D = Ah*Bh + Ah*Bl + Al*Bh accumulated in fp32 -> ~fp32-grade accuracy.
// 128x128 tile, BK=32, 256 threads (4 waves, each 64x64 = 4x4 MFMA frags).
// ---------------------------------------------------------------------------
__global__ __launch_bounds__(256) void gemm_nt_bf16split(const float* __restrict__ A,
                                                         const float* __restrict__ W,
                                                         float* __restrict__ C)
{
    // padded row stride 40 shorts = 80B (16B-aligned rows, spreads banks)
    __shared__ unsigned short Ah[128][40], Al[128][40], Bh[128][40], Bl[128][40];
    const int t    = threadIdx.x;
    const int lane = t & 63, wave = t >> 6;
    const int wm   = wave >> 1, wn = wave & 1;
    const int m0   = blockIdx.x * 128, n0 = blockIdx.y * 128;
    const int fr   = lane & 15;          // A/B frag row (m or n within 16)
    const int kq   = (lane >> 4) * 8;    // k offset of this lane's 8 elements

    f32x4 acc[4][4];
    #pragma unroll
    for (int i = 0; i < 4; ++i)
        #pragma unroll
        for (int j = 0; j < 4; ++j) acc[i][j] = 0.f;

    for (int k0 = 0; k0 < D_; k0 += 32) {
        // ---- stage 128x32 fp32 of A and W, split to bf16 hi/lo in LDS ----
        #pragma unroll
        for (int r = 0; r < 4; ++r) {
            int idx = t + r * 256;               // 1024 float4s per matrix
            int row = idx >> 3, c4 = (idx & 7) * 4;
            float4 va = *(const float4*)&A[(size_t)(m0 + row) * D_ + k0 + c4];
            float4 vb = *(const float4*)&W[(size_t)(n0 + row) * D_ + k0 + c4];
            unsigned short ah0 = f2bf(va.x), ah1 = f2bf(va.y), ah2 = f2bf(va.z), ah3 = f2bf(va.w);
            unsigned short bh0 = f2bf(vb.x), bh1 = f2bf(vb.y), bh2 = f2bf(vb.z), bh3 = f2bf(vb.w);
            *(ushort4*)&Ah[row][c4] = make_ushort4(ah0, ah1, ah2, ah3);
            *(ushort4*)&Bh[row][c4] = make_ushort4(bh0, bh1, bh2, bh3);
            *(ushort4*)&Al[row][c4] = make_ushort4(f2bf(va.x - bf2f(ah0)), f2bf(va.y - bf2f(ah1)),
                                                   f2bf(va.z - bf2f(ah2)), f2bf(va.w - bf2f(ah3)));
            *(ushort4*)&Bl[row][c4] = make_ushort4(f2bf(vb.x - bf2f(bh0)), f2bf(vb.y - bf2f(bh1)),
                                                   f2bf(vb.z - bf2f(bh2)), f2bf(vb.w - bf2f(bh3)));
        }
        __syncthreads();

        // ---- fragments + MFMA ----
        s16x8 ah[4], al[4];
        #pragma unroll
        for (int mi = 0; mi < 4; ++mi) {
            ah[mi] = *(const s16x8*)&Ah[wm * 64 + mi * 16 + fr][kq];
            al[mi] = *(const s16x8*)&Al[wm * 64 + mi * 16 + fr][kq];
        }
        #pragma unroll
        for (int ni = 0; ni < 4; ++ni) {
            s16x8 bh = *(const s16x8*)&Bh[wn * 64 + ni * 16 + fr][kq];
            s16x8 bl = *(const s16x8*)&Bl[wn * 64 + ni * 16 + fr][kq];
            #pragma unroll
            for (int mi = 0; mi < 4; ++mi) {
                acc[mi][ni] = __builtin_amdgcn_mfma_f32_16x16x32_bf16(ah[mi], bh, acc[mi][ni], 0, 0, 0);
                acc[mi][ni] = __builtin_amdgcn_mfma_f32_16x16x32_bf16(ah[mi], bl, acc[mi][ni], 0, 0, 0);
                acc[mi][ni] = __builtin_amdgcn_mfma_f32_16x16x32_bf16(al[mi], bh, acc[mi][ni], 0, 0, 0);
            }
        }
        __syncthreads();
    }

    // ---- epilogue: C/D layout col=lane&15, row=(lane>>4)*4+reg ----
    const int fq = (lane >> 4) * 4;
    #pragma unroll
    for (int mi = 0; mi < 4; ++mi)
        #pragma unroll
        for (int ni = 0; ni < 4; ++ni)
            #pragma unroll
            for (int r = 0; r < 4; ++r)
                C[(size_t)(m0 + wm * 64 + mi * 16 + fq + r) * D_ + n0 + wn * 64 + ni * 16 + fr] =
                    acc[mi][ni][r];
}

// ---------------------------------------------------------------------------
// Fused per-bt edge scores + segment softmax + aggregation.
// One block per bt. LDS: Xq[bt] 64KB + Xv[bt] 64KB + e/w 8KB + edge lists.
// ---------------------------------------------------------------------------
__global__ __launch_bounds__(256) void fused_edge_agg(
    const float* __restrict__ Xq, const float* __restrict__ Xv,
    const int* __restrict__ gsrc, const int* __restrict__ gdst,
    const float* __restrict__ a, const float* __restrict__ logA0,
    const int* __restrict__ csr_off, const int* __restrict__ csr_eid,
    float* __restrict__ Y)
{
    extern __shared__ char smem[];
    float* sXq  = (float*)smem;               // 16384 f
    float* sXv  = sXq + NNODE * D_;           // 16384 f
    float* sE   = sXv + NNODE * D_;           // 2048 f  (scores -> weights)
    float* sLog = sE + NE * NHEAD;            // 512 f
    int*   sSrc = (int*)(sLog + NE);          // 512 i
    int*   sDst = sSrc + NE;                  // 512 i

    const int bt   = blockIdx.x;
    const int t    = threadIdx.x;
    const int lane = t & 63, wave = t >> 6;
    const int g    = lane >> 4, lg = lane & 15;   // head group / lane-in-group

    // ---- phase 1: stage ----
    const float4* gq = (const float4*)(Xq + (size_t)bt * NNODE * D_);
    const float4* gv = (const float4*)(Xv + (size_t)bt * NNODE * D_);
    float4* sq4 = (float4*)sXq;
    float4* sv4 = (float4*)sXv;
    #pragma unroll
    for (int i = 0; i < 16; ++i) {
        sq4[t + i * 256] = gq[t + i * 256];
        sv4[t + i * 256] = gv[t + i * 256];
    }
    sSrc[t] = gsrc[t];         sSrc[t + 256] = gsrc[t + 256];
    sDst[t] = gdst[t];         sDst[t + 256] = gdst[t + 256];
    sLog[t] = logA0[t];        sLog[t + 256] = logA0[t + 256];
    const float4 areg = ((const float4*)a)[lane];   // a for dims lane*4..+3 (head g)
    __syncthreads();

    // ---- phase 2: edge scores. wave handles 128 edges; 16-lane group per head ----
    for (int i = 0; i < 128; ++i) {
        int e = wave * 128 + i;
        int s = sSrc[e], d = sDst[e];
        float4 q = sq4[s * 64 + lane];
        float4 k = sq4[d * 64 + lane];
        float x0 = q.x + k.x, x1 = q.y + k.y, x2 = q.z + k.z, x3 = q.w + k.w;
        x0 = x0 > 0.f ? x0 : SLOPE * x0;
        x1 = x1 > 0.f ? x1 : SLOPE * x1;
        x2 = x2 > 0.f ? x2 : SLOPE * x2;
        x3 = x3 > 0.f ? x3 : SLOPE * x3;
        float p = x0 * areg.x + x1 * areg.y + x2 * areg.z + x3 * areg.w;
        p += __shfl_xor(p, 1);
        p += __shfl_xor(p, 2);
        p += __shfl_xor(p, 4);
        p += __shfl_xor(p, 8);
        if (lg == 0) sE[e * 4 + g] = p + sLog[e];
    }
    __syncthreads();

    // ---- phase 3a: segment softmax normalize, one (node, head) per thread ----
    {
        int n = t >> 2, h = t & 3;
        int o0 = csr_off[n], o1 = csr_off[n + 1];
        float m = -INFINITY;
        for (int i = o0; i < o1; ++i) m = fmaxf(m, sE[csr_eid[i] * 4 + h]);
        float den = 0.f;
        for (int i = o0; i < o1; ++i) den += __expf(sE[csr_eid[i] * 4 + h] - m);
        float inv = (o1 > o0) ? 1.f / den : 0.f;
        for (int i = o0; i < o1; ++i) {
            int eid = csr_eid[i];
            sE[eid * 4 + h] = __expf(sE[eid * 4 + h] - m) * inv;
        }
    }
    __syncthreads();

    // ---- phase 3b: aggregate. wave w handles nodes w, w+4, ... ----
    float4* y4 = (float4*)(Y + (size_t)bt * NNODE * D_);
    for (int ii = 0; ii < 16; ++ii) {
        int n = wave + ii * 4;
        int o0 = csr_off[n], o1 = csr_off[n + 1];
        float ax = 0.f, ay = 0.f, az = 0.f, aw = 0.f;
        for (int i = o0; i < o1; ++i) {
            int eid = csr_eid[i];
            float w = sE[eid * 4 + g];
            float4 v = sv4[sDst[eid] * 64 + lane];
            ax += w * v.x; ay += w * v.y; az += w * v.z; aw += w * v.w;
        }
        y4[n * 64 + lane] = make_float4(ax, ay, az, aw);
    }
}

// ---------------------------------------------------------------------------
extern "C" void kernel_launch(void* const* d_in, const int* in_sizes, int n_in,
                              void* d_out, int out_size, void* d_ws, size_t ws_size,
                              hipStream_t stream)
{
    const float* H     = (const float*)d_in[0];
    const float* W_lin = (const float*)d_in[1];
    const float* W_val = (const float*)d_in[2];
    const float* a     = (const float*)d_in[3];
    const float* W_out = (const float*)d_in[4];
    const float* A0    = (const float*)d_in[5];
    const int*   src   = (const int*)d_in[6];
    const int*   dst   = (const int*)d_in[7];
    float* out = (float*)d_out;

    const size_t nX = (size_t)BTN * D_;          // 16.7M floats
    float* Xq    = (float*)d_ws;
    float* Xv    = Xq + nX;
    float* logA0 = Xv + nX;
    int*   csr_off = (int*)(logA0 + NE);
    int*   csr_eid = csr_off + (NNODE + 1);
    size_t need = (size_t)((char*)(csr_eid + NE) - (char*)d_ws);
    if (ws_size < need) return;

    build_csr<<<1, 64, 0, stream>>>(src, dst, A0, csr_off, csr_eid, logA0);

    dim3 gg(BTN / 128, D_ / 128);
    gemm_nt_bf16split<<<gg, 256, 0, stream>>>(H, W_lin, Xq);
    gemm_nt_bf16split<<<gg, 256, 0, stream>>>(H, W_val, Xv);

    const int smem_bytes = (NNODE * D_ * 2 + NE * NHEAD + NE) * 4 + NE * 4 * 2;  // 145408
    float* Y = Xq;  // block bt reads Xq[bt] into LDS before writing Y[bt]; regions per-bt disjoint
    fused_edge_agg<<<1024, 256, smem_bytes, stream>>>(Xq, Xv, src, dst, a, logA0,
                                                      csr_off, csr_eid, Y);

    gemm_nt_bf16split<<<gg, 256, 0, stream>>>(Y, W_out, out);
}

// Round 3
// 289.447 us; speedup vs baseline: 3.4876x; 2.1411x over previous
//
#include <hip/hip_runtime.h>
#include <math.h>

#define D_    256
#define NE    512
#define NNODE 64
#define NHEAD 4
#define SLOPE 0.2f
#define BTN   65536

typedef __attribute__((ext_vector_type(4))) float f32x4;
typedef __attribute__((ext_vector_type(8))) short s16x8;
typedef unsigned short u16;

__device__ inline u16 f2bf(float x) {
    union { float f; unsigned u; } v; v.f = x;
    unsigned r = v.u + 0x7fff + ((v.u >> 16) & 1);
    return (u16)(r >> 16);
}
__device__ inline float bf2f(u16 b) {
    union { float f; unsigned u; } v; v.u = ((unsigned)b) << 16;
    return v.f;
}

#define GLD16(g, l) __builtin_amdgcn_global_load_lds( \
    (const __attribute__((address_space(1))) void*)(g), \
    (__attribute__((address_space(3))) void*)(l), 16, 0, 0)

// ---------------------------------------------------------------------------
// Parallel deterministic CSR build + log(A0+eps). One block, 512 threads.
// ---------------------------------------------------------------------------
__global__ __launch_bounds__(512) void build_csr(const int* __restrict__ src,
    const int* __restrict__ dst, const float* __restrict__ A0,
    int* __restrict__ csr_off, int* __restrict__ csr_eid, float* __restrict__ logA0)
{
    __shared__ int sS[NE];
    __shared__ int sCnt[NNODE];
    __shared__ int sOf[NNODE + 1];
    const int t = threadIdx.x;
    sS[t] = src[t];
    __syncthreads();
    if (t < NNODE) {
        int c = 0;
        for (int e = 0; e < NE; ++e) c += (sS[e] == t);
        sCnt[t] = c;
    }
    __syncthreads();
    if (t == 0) {
        int run = 0;
        for (int n = 0; n < NNODE; ++n) { sOf[n] = run; run += sCnt[n]; }
        sOf[NNODE] = run;
    }
    __syncthreads();
    {
        int s = sS[t];
        int rank = 0;
        for (int e = 0; e < NE; ++e) rank += (int)((sS[e] == s) && (e < t));
        csr_eid[sOf[s] + rank] = t;                 // stable order within segment
        logA0[t] = logf(A0[s * NNODE + dst[t]] + 1e-8f);
    }
    if (t <= NNODE) csr_off[t] = sOf[t];
}

// ---------------------------------------------------------------------------
// fp32 -> split bf16 (hi + lo), grid-stride over float4s.
// ---------------------------------------------------------------------------
__global__ __launch_bounds__(256) void prep_split(const float* __restrict__ s,
    u16* __restrict__ h, u16* __restrict__ l, int n4)
{
    for (int i = blockIdx.x * 256 + threadIdx.x; i < n4; i += gridDim.x * 256) {
        float4 v = ((const float4*)s)[i];
        u16 h0 = f2bf(v.x), h1 = f2bf(v.y), h2 = f2bf(v.z), h3 = f2bf(v.w);
        ((ushort4*)h)[i] = make_ushort4(h0, h1, h2, h3);
        ((ushort4*)l)[i] = make_ushort4(f2bf(v.x - bf2f(h0)), f2bf(v.y - bf2f(h1)),
                                        f2bf(v.z - bf2f(h2)), f2bf(v.w - bf2f(h3)));
    }
}

// ---------------------------------------------------------------------------
// Split-bf16 MFMA GEMM, pre-split operands, global_load_lds staging.
// C[m][n] = sum_k (Ah+Al)[m][k] * (Bh+Bl)[n][k]   (3-pass: hh + hl + lh)
// 128x128 tile, BK=32, 256 threads (4 waves, each 64x64).
// ---------------------------------------------------------------------------
template<bool OUT_BF16>
__global__ __launch_bounds__(256) void gemm_bf16s(const u16* __restrict__ Ah,
    const u16* __restrict__ Al, const u16* __restrict__ Bh, const u16* __restrict__ Bl,
    void* __restrict__ Cout)
{
    __shared__ u16 sAh[4096], sAl[4096], sBh[4096], sBl[4096];  // [128][32] each, linear
    const int t = threadIdx.x, lane = t & 63, wave = t >> 6;
    const int wm = wave >> 1, wn = wave & 1;
    const int m0 = blockIdx.x * 128, n0 = blockIdx.y * 128;
    const int fr = lane & 15, kq = (lane >> 4) * 8;

    f32x4 acc[4][4];
    #pragma unroll
    for (int i = 0; i < 4; ++i)
        #pragma unroll
        for (int j = 0; j < 4; ++j) acc[i][j] = 0.f;

    for (int k0 = 0; k0 < D_; k0 += 32) {
        // stage 4 x 8KB tiles; chunk c (16B) <-> row = c>>2, k-slot = (c&3)*8
        #pragma unroll
        for (int s = 0; s < 2; ++s) {
            const int cb = (s * 4 + wave) * 64;
            const int c  = cb + lane;
            const int row = c >> 2, ks = (c & 3) * 8;
            const size_t ga = (size_t)(m0 + row) * D_ + k0 + ks;
            const size_t gb = (size_t)(n0 + row) * D_ + k0 + ks;
            GLD16(Ah + ga, sAh + cb * 8);
            GLD16(Al + ga, sAl + cb * 8);
            GLD16(Bh + gb, sBh + cb * 8);
            GLD16(Bl + gb, sBl + cb * 8);
        }
        __syncthreads();   // drains vmcnt -> LDS tiles ready

        s16x8 fah[4], fal[4];
        #pragma unroll
        for (int mi = 0; mi < 4; ++mi) {
            fah[mi] = *(const s16x8*)(sAh + (wm * 64 + mi * 16 + fr) * 32 + kq);
            fal[mi] = *(const s16x8*)(sAl + (wm * 64 + mi * 16 + fr) * 32 + kq);
        }
        #pragma unroll
        for (int ni = 0; ni < 4; ++ni) {
            s16x8 fbh = *(const s16x8*)(sBh + (wn * 64 + ni * 16 + fr) * 32 + kq);
            s16x8 fbl = *(const s16x8*)(sBl + (wn * 64 + ni * 16 + fr) * 32 + kq);
            #pragma unroll
            for (int mi = 0; mi < 4; ++mi) {
                acc[mi][ni] = __builtin_amdgcn_mfma_f32_16x16x32_bf16(fah[mi], fbh, acc[mi][ni], 0, 0, 0);
                acc[mi][ni] = __builtin_amdgcn_mfma_f32_16x16x32_bf16(fah[mi], fbl, acc[mi][ni], 0, 0, 0);
                acc[mi][ni] = __builtin_amdgcn_mfma_f32_16x16x32_bf16(fal[mi], fbh, acc[mi][ni], 0, 0, 0);
            }
        }
        __syncthreads();
    }

    const int fq = (lane >> 4) * 4;   // C/D: col = lane&15, row = (lane>>4)*4 + reg
    #pragma unroll
    for (int mi = 0; mi < 4; ++mi)
        #pragma unroll
        for (int ni = 0; ni < 4; ++ni)
            #pragma unroll
            for (int r = 0; r < 4; ++r) {
                size_t off = (size_t)(m0 + wm * 64 + mi * 16 + fq + r) * D_
                           + n0 + wn * 64 + ni * 16 + fr;
                if (OUT_BF16) ((u16*)Cout)[off] = f2bf(acc[mi][ni][r]);
                else          ((float*)Cout)[off] = acc[mi][ni][r];
            }
}

// ---------------------------------------------------------------------------
// Fused edge scores + segment softmax + aggregation, one block per (bt, head).
// Reads Xq fp32, Xv bf16; writes Y as split bf16 (Yh, Yl).
// ---------------------------------------------------------------------------
__global__ __launch_bounds__(256) void fused_edge_agg(
    const float* __restrict__ Xq, const u16* __restrict__ Xvb,
    const int* __restrict__ gsrc, const int* __restrict__ gdst,
    const float* __restrict__ a,
    const float* __restrict__ logA0, const int* __restrict__ csr_off,
    const int* __restrict__ csr_eid,
    u16* __restrict__ Yh, u16* __restrict__ Yl)
{
    __shared__ float sQ[64 * 64];     // 16 KB, [node][dim] this head's slice
    __shared__ float sV[64 * 64];     // 16 KB
    __shared__ float sE[NE];          // scores -> weights
    __shared__ float sLog[NE];
    __shared__ int   sSrc[NE], sDst[NE], sEid[NE];
    __shared__ int   sOff[NNODE + 1];

    const int t = threadIdx.x;
    const int grp = t >> 4, lg = t & 15;      // 16 groups x 16 lanes
    const int bt = blockIdx.x >> 2, h = blockIdx.x & 3;

    // ---- stage Q (fp32) and V (bf16 -> fp32) slices, lists ----
    const float* gq = Xq + (size_t)bt * NNODE * D_ + h * 64;
    #pragma unroll
    for (int r = 0; r < 4; ++r) {
        int id = r * 256 + t;                  // 1024 float4s
        int row = id >> 4, c4 = id & 15;
        ((float4*)sQ)[id] = *(const float4*)&gq[(size_t)row * D_ + c4 * 4];
    }
    const u16* gv = Xvb + (size_t)bt * NNODE * D_ + h * 64;
    #pragma unroll
    for (int r = 0; r < 2; ++r) {
        int id = r * 256 + t;                  // 512 x 16B chunks
        int row = id >> 3, c8 = id & 7;
        s16x8 v = *(const s16x8*)&gv[(size_t)row * D_ + c8 * 8];
        float* dptr = &sV[row * 64 + c8 * 8];
        #pragma unroll
        for (int k = 0; k < 8; ++k) dptr[k] = bf2f((u16)v[k]);
    }
    sSrc[t] = gsrc[t];  sSrc[t + 256] = gsrc[t + 256];
    sDst[t] = gdst[t];  sDst[t + 256] = gdst[t + 256];
    sEid[t] = csr_eid[t]; sEid[t + 256] = csr_eid[t + 256];
    sLog[t] = logA0[t]; sLog[t + 256] = logA0[t + 256];
    if (t <= NNODE) sOff[t] = csr_off[t];
    const float4 areg = *(const float4*)&a[h * 64 + lg * 4];
    __syncthreads();

    // ---- edge scores: group handles 32 edges, 16 lanes x float4 = 64 dims ----
    for (int it = 0; it < 32; ++it) {
        int e = grp * 32 + it;
        int s_ = sSrc[e], d_ = sDst[e];
        float4 q = ((const float4*)sQ)[s_ * 16 + lg];
        float4 k = ((const float4*)sQ)[d_ * 16 + lg];
        float x0 = q.x + k.x, x1 = q.y + k.y, x2 = q.z + k.z, x3 = q.w + k.w;
        x0 = x0 > 0.f ? x0 : SLOPE * x0;
        x1 = x1 > 0.f ? x1 : SLOPE * x1;
        x2 = x2 > 0.f ? x2 : SLOPE * x2;
        x3 = x3 > 0.f ? x3 : SLOPE * x3;
        float p = x0 * areg.x + x1 * areg.y + x2 * areg.z + x3 * areg.w;
        p += __shfl_xor(p, 1);
        p += __shfl_xor(p, 2);
        p += __shfl_xor(p, 4);
        p += __shfl_xor(p, 8);
        if (lg == 0) sE[e] = p + sLog[e];
    }
    __syncthreads();

    // ---- segment softmax normalize: thread t<64 owns node t ----
    if (t < NNODE) {
        int o0 = sOff[t], o1 = sOff[t + 1];
        float m = -INFINITY;
        for (int i = o0; i < o1; ++i) m = fmaxf(m, sE[sEid[i]]);
        float den = 0.f;
        for (int i = o0; i < o1; ++i) den += __expf(sE[sEid[i]] - m);
        float inv = 1.f / den;
        for (int i = o0; i < o1; ++i) { int e = sEid[i]; sE[e] = __expf(sE[e] - m) * inv; }
    }
    __syncthreads();

    // ---- aggregate: group owns 4 nodes; write Y as split bf16 ----
    u16* yh = Yh + (size_t)bt * NNODE * D_ + h * 64;
    u16* yl = Yl + (size_t)bt * NNODE * D_ + h * 64;
    #pragma unroll
    for (int j = 0; j < 4; ++j) {
        int n = grp * 4 + j;
        int o0 = sOff[n], o1 = sOff[n + 1];
        float ax = 0.f, ay = 0.f, az = 0.f, aw = 0.f;
        for (int i = o0; i < o1; ++i) {
            int e = sEid[i];
            float w = sE[e];
            float4 v = ((const float4*)sV)[sDst[e] * 16 + lg];
            ax += w * v.x; ay += w * v.y; az += w * v.z; aw += w * v.w;
        }
        u16 h0 = f2bf(ax), h1 = f2bf(ay), h2 = f2bf(az), h3 = f2bf(aw);
        *(ushort4*)&yh[(size_t)n * D_ + lg * 4] = make_ushort4(h0, h1, h2, h3);
        *(ushort4*)&yl[(size_t)n * D_ + lg * 4] =
            make_ushort4(f2bf(ax - bf2f(h0)), f2bf(ay - bf2f(h1)),
                         f2bf(az - bf2f(h2)), f2bf(aw - bf2f(h3)));
    }
}

// ---------------------------------------------------------------------------
extern "C" void kernel_launch(void* const* d_in, const int* in_sizes, int n_in,
                              void* d_out, int out_size, void* d_ws, size_t ws_size,
                              hipStream_t stream)
{
    const float* H     = (const float*)d_in[0];
    const float* W_lin = (const float*)d_in[1];
    const float* W_val = (const float*)d_in[2];
    const float* a     = (const float*)d_in[3];
    const float* W_out = (const float*)d_in[4];
    const float* A0    = (const float*)d_in[5];
    const int*   src   = (const int*)d_in[6];
    const int*   dst   = (const int*)d_in[7];

    const size_t nX = (size_t)BTN * D_;              // 16777216 elems
    // ws: Hh | Hl | Xq(fp32)  == 134217728 B exactly (proven available)
    u16*   Hh = (u16*)d_ws;
    u16*   Hl = Hh + nX;
    float* Xq = (float*)(Hl + nX);
    u16*   Yh = Hh;                                  // alias: H dead after GEMM2
    u16*   Yl = Hl;
    u16*   Wouth = (u16*)Xq;                         // alias: Xq dead after fused
    u16*   Woutl = Wouth + D_ * D_;
    if (ws_size < (size_t)134217728) return;

    // d_out scratch until GEMM3: Xv bf16 [0,33.5MB) ; lists/W-splits at +40MB
    u16*   Xvb = (u16*)d_out;
    char*  sc2 = (char*)d_out + (size_t)40 * 1024 * 1024;
    float* logA0   = (float*)sc2;                    // 2 KB
    int*   csr_off = (int*)(sc2 + 4096);
    int*   csr_eid = (int*)(sc2 + 8192);
    u16*   Wlh = (u16*)(sc2 + 16384);                // 128 KB each
    u16*   Wll = Wlh + D_ * D_;
    u16*   Wvh = Wll + D_ * D_;
    u16*   Wvl = Wvh + D_ * D_;

    build_csr<<<1, 512, 0, stream>>>(src, dst, A0, csr_off, csr_eid, logA0);
    prep_split<<<4096, 256, 0, stream>>>(H, Hh, Hl, (int)(nX / 4));
    prep_split<<<64, 256, 0, stream>>>(W_lin, Wlh, Wll, D_ * D_ / 4);
    prep_split<<<64, 256, 0, stream>>>(W_val, Wvh, Wvl, D_ * D_ / 4);

    dim3 gg(BTN / 128, D_ / 128);
    gemm_bf16s<false><<<gg, 256, 0, stream>>>(Hh, Hl, Wlh, Wll, Xq);
    gemm_bf16s<true ><<<gg, 256, 0, stream>>>(Hh, Hl, Wvh, Wvl, Xvb);

    fused_edge_agg<<<4096, 256, 0, stream>>>(Xq, Xvb, src, dst, a, logA0,
                                             csr_off, csr_eid, Yh, Yl);

    prep_split<<<64, 256, 0, stream>>>(W_out, Wouth, Woutl, D_ * D_ / 4);
    gemm_bf16s<false><<<gg, 256, 0, stream>>>(Yh, Yl, Wouth, Woutl, (float*)d_out);
}

// Round 4
// 254.720 us; speedup vs baseline: 3.9631x; 1.1363x over previous
//
#include <hip/hip_runtime.h>
#include <math.h>

#define D_    256
#define NE    512
#define NNODE 64
#define NHEAD 4
#define SLOPE 0.2f
#define BTN   65536

typedef __attribute__((ext_vector_type(4))) float f32x4;
typedef __attribute__((ext_vector_type(8))) short s16x8;
typedef unsigned short u16;

__device__ inline u16 f2bf(float x) {
    union { float f; unsigned u; } v; v.f = x;
    unsigned r = v.u + 0x7fff + ((v.u >> 16) & 1);
    return (u16)(r >> 16);
}
__device__ inline float bf2f(u16 b) {
    union { float f; unsigned u; } v; v.u = ((unsigned)b) << 16;
    return v.f;
}

#define GLD16(g, l) __builtin_amdgcn_global_load_lds( \
    (const __attribute__((address_space(1))) void*)(g), \
    (__attribute__((address_space(3))) void*)(l), 16, 0, 0)

// ---------------------------------------------------------------------------
// Parallel deterministic CSR build + log(A0+eps). One block, 512 threads.
// ---------------------------------------------------------------------------
__global__ __launch_bounds__(512) void build_csr(const int* __restrict__ src,
    const int* __restrict__ dst, const float* __restrict__ A0,
    int* __restrict__ csr_off, int* __restrict__ csr_eid, float* __restrict__ logA0)
{
    __shared__ int sS[NE];
    __shared__ int sCnt[NNODE];
    __shared__ int sOf[NNODE + 1];
    const int t = threadIdx.x;
    sS[t] = src[t];
    __syncthreads();
    if (t < NNODE) {
        int c = 0;
        for (int e = 0; e < NE; ++e) c += (sS[e] == t);
        sCnt[t] = c;
    }
    __syncthreads();
    if (t == 0) {
        int run = 0;
        for (int n = 0; n < NNODE; ++n) { sOf[n] = run; run += sCnt[n]; }
        sOf[NNODE] = run;
    }
    __syncthreads();
    {
        int s = sS[t];
        int rank = 0;
        for (int e = 0; e < NE; ++e) rank += (int)((sS[e] == s) && (e < t));
        csr_eid[sOf[s] + rank] = t;                 // stable order within segment
        logA0[t] = logf(A0[s * NNODE + dst[t]] + 1e-8f);
    }
    if (t <= NNODE) csr_off[t] = sOf[t];
}

// ---------------------------------------------------------------------------
// fp32 -> split bf16 (hi + lo), grid-stride over float4s.
// ---------------------------------------------------------------------------
__global__ __launch_bounds__(256) void prep_split(const float* __restrict__ s,
    u16* __restrict__ h, u16* __restrict__ l, int n4)
{
    for (int i = blockIdx.x * 256 + threadIdx.x; i < n4; i += gridDim.x * 256) {
        float4 v = ((const float4*)s)[i];
        u16 h0 = f2bf(v.x), h1 = f2bf(v.y), h2 = f2bf(v.z), h3 = f2bf(v.w);
        ((ushort4*)h)[i] = make_ushort4(h0, h1, h2, h3);
        ((ushort4*)l)[i] = make_ushort4(f2bf(v.x - bf2f(h0)), f2bf(v.y - bf2f(h1)),
                                        f2bf(v.z - bf2f(h2)), f2bf(v.w - bf2f(h3)));
    }
}

// ---------------------------------------------------------------------------
// Split-bf16 MFMA GEMM, pre-split operands, global_load_lds staging.
// 128x128 tile, BK=32, 256 threads (4 waves, each 64x64).
// ---------------------------------------------------------------------------
template<bool OUT_BF16>
__global__ __launch_bounds__(256) void gemm_bf16s(const u16* __restrict__ Ah,
    const u16* __restrict__ Al, const u16* __restrict__ Bh, const u16* __restrict__ Bl,
    void* __restrict__ Cout)
{
    __shared__ u16 sAh[4096], sAl[4096], sBh[4096], sBl[4096];  // [128][32] each, linear
    const int t = threadIdx.x, lane = t & 63, wave = t >> 6;
    const int wm = wave >> 1, wn = wave & 1;
    const int m0 = blockIdx.x * 128, n0 = blockIdx.y * 128;
    const int fr = lane & 15, kq = (lane >> 4) * 8;

    f32x4 acc[4][4];
    #pragma unroll
    for (int i = 0; i < 4; ++i)
        #pragma unroll
        for (int j = 0; j < 4; ++j) acc[i][j] = 0.f;

    for (int k0 = 0; k0 < D_; k0 += 32) {
        #pragma unroll
        for (int s = 0; s < 2; ++s) {
            const int cb = (s * 4 + wave) * 64;
            const int c  = cb + lane;
            const int row = c >> 2, ks = (c & 3) * 8;
            const size_t ga = (size_t)(m0 + row) * D_ + k0 + ks;
            const size_t gb = (size_t)(n0 + row) * D_ + k0 + ks;
            GLD16(Ah + ga, sAh + cb * 8);
            GLD16(Al + ga, sAl + cb * 8);
            GLD16(Bh + gb, sBh + cb * 8);
            GLD16(Bl + gb, sBl + cb * 8);
        }
        __syncthreads();

        s16x8 fah[4], fal[4];
        #pragma unroll
        for (int mi = 0; mi < 4; ++mi) {
            fah[mi] = *(const s16x8*)(sAh + (wm * 64 + mi * 16 + fr) * 32 + kq);
            fal[mi] = *(const s16x8*)(sAl + (wm * 64 + mi * 16 + fr) * 32 + kq);
        }
        #pragma unroll
        for (int ni = 0; ni < 4; ++ni) {
            s16x8 fbh = *(const s16x8*)(sBh + (wn * 64 + ni * 16 + fr) * 32 + kq);
            s16x8 fbl = *(const s16x8*)(sBl + (wn * 64 + ni * 16 + fr) * 32 + kq);
            #pragma unroll
            for (int mi = 0; mi < 4; ++mi) {
                acc[mi][ni] = __builtin_amdgcn_mfma_f32_16x16x32_bf16(fah[mi], fbh, acc[mi][ni], 0, 0, 0);
                acc[mi][ni] = __builtin_amdgcn_mfma_f32_16x16x32_bf16(fah[mi], fbl, acc[mi][ni], 0, 0, 0);
                acc[mi][ni] = __builtin_amdgcn_mfma_f32_16x16x32_bf16(fal[mi], fbh, acc[mi][ni], 0, 0, 0);
            }
        }
        __syncthreads();
    }

    const int fq = (lane >> 4) * 4;   // C/D: col = lane&15, row = (lane>>4)*4 + reg
    #pragma unroll
    for (int mi = 0; mi < 4; ++mi)
        #pragma unroll
        for (int ni = 0; ni < 4; ++ni)
            #pragma unroll
            for (int r = 0; r < 4; ++r) {
                size_t off = (size_t)(m0 + wm * 64 + mi * 16 + fq + r) * D_
                           + n0 + wn * 64 + ni * 16 + fr;
                if (OUT_BF16) ((u16*)Cout)[off] = f2bf(acc[mi][ni][r]);
                else          ((float*)Cout)[off] = acc[mi][ni][r];
            }
}

// ---------------------------------------------------------------------------
// Fused edge scores + segment softmax + aggregation, one block per (bt, head).
// Q staged fp32 (16KB), V staged bf16 (8KB) via global_load_lds; ~33KB LDS
// -> 4 blocks/CU. Quad-parallel softmax; 1/den folded into aggregation.
// ---------------------------------------------------------------------------
__global__ __launch_bounds__(256) void fused_edge_agg(
    const float* __restrict__ Xq, const u16* __restrict__ Xvb,
    const int* __restrict__ gsrc, const int* __restrict__ gdst,
    const float* __restrict__ a,
    const float* __restrict__ logA0, const int* __restrict__ csr_off,
    const int* __restrict__ csr_eid,
    u16* __restrict__ Yh, u16* __restrict__ Yl)
{
    __shared__ float sQ[NNODE * 64];      // 16 KB  [node][dim] fp32
    __shared__ u16   sV[NNODE * 64];      // 8 KB   [node][dim] bf16
    __shared__ float sE[NE];              // scores -> unnormalized weights
    __shared__ float sLog[NE];
    __shared__ int   sPack[NE];           // (src<<8)|dst
    __shared__ int   sEid[NE];
    __shared__ float sDen[NNODE];         // 1/denominator
    __shared__ int   sOff[NNODE + 1];

    const int t = threadIdx.x;
    const int grp = t >> 4, lg = t & 15;      // 16 groups x 16 lanes
    const int bt = blockIdx.x >> 2, h = blockIdx.x & 3;

    // ---- stage Q (fp32) and V (bf16) head slices via global_load_lds ----
    const float* gq = Xq + (size_t)bt * NNODE * D_ + h * 64;
    {
        int id = t;                            // 1024 16B chunks, 4 rounds
        #pragma unroll
        for (int r = 0; r < 4; ++r, id += 256) {
            int row = id >> 4, c4 = id & 15;
            GLD16(gq + (size_t)row * D_ + c4 * 4, (char*)sQ + id * 16);
        }
    }
    const u16* gv = Xvb + (size_t)bt * NNODE * D_ + h * 64;
    {
        int id = t;                            // 512 16B chunks, 2 rounds
        #pragma unroll
        for (int r = 0; r < 2; ++r, id += 256) {
            int row = id >> 3, c8 = id & 7;
            GLD16(gv + (size_t)row * D_ + c8 * 8, (char*)sV + id * 16);
        }
    }
    sPack[t]       = (gsrc[t] << 8)       | gdst[t];
    sPack[t + 256] = (gsrc[t + 256] << 8) | gdst[t + 256];
    sEid[t] = csr_eid[t]; sEid[t + 256] = csr_eid[t + 256];
    sLog[t] = logA0[t];   sLog[t + 256] = logA0[t + 256];
    if (t <= NNODE) sOff[t] = csr_off[t];
    const float4 areg = *(const float4*)&a[h * 64 + lg * 4];
    __syncthreads();   // drains global_load_lds (vmcnt) + lds writes

    // ---- edge scores: group handles 32 edges, 16 lanes x 4 dims ----
    for (int it = 0; it < 32; ++it) {
        int e = grp * 32 + it;
        int pk = sPack[e];
        int s_ = pk >> 8, d_ = pk & 255;
        float4 q = ((const float4*)sQ)[s_ * 16 + lg];
        float4 k = ((const float4*)sQ)[d_ * 16 + lg];
        float x0 = q.x + k.x, x1 = q.y + k.y, x2 = q.z + k.z, x3 = q.w + k.w;
        x0 = x0 > 0.f ? x0 : SLOPE * x0;
        x1 = x1 > 0.f ? x1 : SLOPE * x1;
        x2 = x2 > 0.f ? x2 : SLOPE * x2;
        x3 = x3 > 0.f ? x3 : SLOPE * x3;
        float p = x0 * areg.x + x1 * areg.y + x2 * areg.z + x3 * areg.w;
        p += __shfl_xor(p, 1);
        p += __shfl_xor(p, 2);
        p += __shfl_xor(p, 4);
        p += __shfl_xor(p, 8);
        if (lg == 0) sE[e] = p + sLog[e];
    }
    __syncthreads();

    // ---- segment softmax: 4 threads per node (quad in same wave) ----
    {
        int n = t >> 2, q = t & 3;
        int o0 = sOff[n], o1 = sOff[n + 1];
        float m = -INFINITY;
        for (int i = o0 + q; i < o1; i += 4) m = fmaxf(m, sE[sEid[i]]);
        m = fmaxf(m, __shfl_xor(m, 1));
        m = fmaxf(m, __shfl_xor(m, 2));
        float den = 0.f;
        for (int i = o0 + q; i < o1; i += 4) {
            int e = sEid[i];
            float w = __expf(sE[e] - m);
            den += w;
            sE[e] = w;                        // unnormalized weight
        }
        den += __shfl_xor(den, 1);
        den += __shfl_xor(den, 2);
        if (q == 0) sDen[n] = (o1 > o0) ? 1.f / den : 0.f;
    }
    __syncthreads();

    // ---- aggregate: group owns 4 nodes; scale by 1/den; split-bf16 output ----
    u16* yh = Yh + (size_t)bt * NNODE * D_ + h * 64;
    u16* yl = Yl + (size_t)bt * NNODE * D_ + h * 64;
    #pragma unroll
    for (int j = 0; j < 4; ++j) {
        int n = grp * 4 + j;
        int o0 = sOff[n], o1 = sOff[n + 1];
        float ax = 0.f, ay = 0.f, az = 0.f, aw = 0.f;
        for (int i = o0; i < o1; ++i) {
            int e = sEid[i];
            float w = sE[e];
            int d_ = sPack[e] & 255;
            ushort4 v = *(const ushort4*)&sV[d_ * 64 + lg * 4];
            ax += w * bf2f(v.x); ay += w * bf2f(v.y);
            az += w * bf2f(v.z); aw += w * bf2f(v.w);
        }
        float inv = sDen[n];
        ax *= inv; ay *= inv; az *= inv; aw *= inv;
        u16 h0 = f2bf(ax), h1 = f2bf(ay), h2 = f2bf(az), h3 = f2bf(aw);
        *(ushort4*)&yh[(size_t)n * D_ + lg * 4] = make_ushort4(h0, h1, h2, h3);
        *(ushort4*)&yl[(size_t)n * D_ + lg * 4] =
            make_ushort4(f2bf(ax - bf2f(h0)), f2bf(ay - bf2f(h1)),
                         f2bf(az - bf2f(h2)), f2bf(aw - bf2f(h3)));
    }
}

// ---------------------------------------------------------------------------
extern "C" void kernel_launch(void* const* d_in, const int* in_sizes, int n_in,
                              void* d_out, int out_size, void* d_ws, size_t ws_size,
                              hipStream_t stream)
{
    const float* H     = (const float*)d_in[0];
    const float* W_lin = (const float*)d_in[1];
    const float* W_val = (const float*)d_in[2];
    const float* a     = (const float*)d_in[3];
    const float* W_out = (const float*)d_in[4];
    const float* A0    = (const float*)d_in[5];
    const int*   src   = (const int*)d_in[6];
    const int*   dst   = (const int*)d_in[7];

    const size_t nX = (size_t)BTN * D_;              // 16777216 elems
    // ws: Hh | Hl | Xq(fp32)  == 134217728 B exactly
    u16*   Hh = (u16*)d_ws;
    u16*   Hl = Hh + nX;
    float* Xq = (float*)(Hl + nX);
    u16*   Yh = Hh;                                  // alias: H dead after GEMM2
    u16*   Yl = Hl;
    u16*   Wouth = (u16*)Xq;                         // alias: Xq dead after fused
    u16*   Woutl = Wouth + D_ * D_;
    if (ws_size < (size_t)134217728) return;

    // d_out scratch until GEMM3: Xv bf16 [0,33.5MB) ; lists/W-splits at +40MB
    u16*   Xvb = (u16*)d_out;
    char*  sc2 = (char*)d_out + (size_t)40 * 1024 * 1024;
    float* logA0   = (float*)sc2;                    // 2 KB
    int*   csr_off = (int*)(sc2 + 4096);
    int*   csr_eid = (int*)(sc2 + 8192);
    u16*   Wlh = (u16*)(sc2 + 16384);                // 128 KB each
    u16*   Wll = Wlh + D_ * D_;
    u16*   Wvh = Wll + D_ * D_;
    u16*   Wvl = Wvh + D_ * D_;

    build_csr<<<1, 512, 0, stream>>>(src, dst, A0, csr_off, csr_eid, logA0);
    prep_split<<<4096, 256, 0, stream>>>(H, Hh, Hl, (int)(nX / 4));
    prep_split<<<64, 256, 0, stream>>>(W_lin, Wlh, Wll, D_ * D_ / 4);
    prep_split<<<64, 256, 0, stream>>>(W_val, Wvh, Wvl, D_ * D_ / 4);

    dim3 gg(BTN / 128, D_ / 128);
    gemm_bf16s<false><<<gg, 256, 0, stream>>>(Hh, Hl, Wlh, Wll, Xq);
    gemm_bf16s<true ><<<gg, 256, 0, stream>>>(Hh, Hl, Wvh, Wvl, Xvb);

    fused_edge_agg<<<4096, 256, 0, stream>>>(Xq, Xvb, src, dst, a, logA0,
                                             csr_off, csr_eid, Yh, Yl);

    prep_split<<<64, 256, 0, stream>>>(W_out, Wouth, Woutl, D_ * D_ / 4);
    gemm_bf16s<false><<<gg, 256, 0, stream>>>(Yh, Yl, Wouth, Woutl, (float*)d_out);
}

// Round 5
// 237.812 us; speedup vs baseline: 4.2448x; 1.0711x over previous
//
#include <hip/hip_runtime.h>
#include <math.h>

#define D_    256
#define NE    512
#define NNODE 64
#define NHEAD 4
#define SLOPE 0.2f
#define BTN   65536

typedef __attribute__((ext_vector_type(4))) float f32x4;
typedef __attribute__((ext_vector_type(8))) short s16x8;
typedef unsigned short u16;

__device__ inline u16 f2bf(float x) {
    union { float f; unsigned u; } v; v.f = x;
    unsigned r = v.u + 0x7fff + ((v.u >> 16) & 1);
    return (u16)(r >> 16);
}
__device__ inline float bf2f(u16 b) {
    union { float f; unsigned u; } v; v.u = ((unsigned)b) << 16;
    return v.f;
}

#define GLD16(g, l) __builtin_amdgcn_global_load_lds( \
    (const __attribute__((address_space(1))) void*)(g), \
    (__attribute__((address_space(3))) void*)(l), 16, 0, 0)

// ---------------------------------------------------------------------------
// Parallel deterministic CSR build + log(A0+eps). One block, 512 threads.
// ---------------------------------------------------------------------------
__global__ __launch_bounds__(512) void build_csr(const int* __restrict__ src,
    const int* __restrict__ dst, const float* __restrict__ A0,
    int* __restrict__ csr_off, int* __restrict__ csr_eid, float* __restrict__ logA0)
{
    __shared__ int sS[NE];
    __shared__ int sCnt[NNODE];
    __shared__ int sOf[NNODE + 1];
    const int t = threadIdx.x;
    sS[t] = src[t];
    __syncthreads();
    if (t < NNODE) {
        int c = 0;
        for (int e = 0; e < NE; ++e) c += (sS[e] == t);
        sCnt[t] = c;
    }
    __syncthreads();
    if (t == 0) {
        int run = 0;
        for (int n = 0; n < NNODE; ++n) { sOf[n] = run; run += sCnt[n]; }
        sOf[NNODE] = run;
    }
    __syncthreads();
    {
        int s = sS[t];
        int rank = 0;
        for (int e = 0; e < NE; ++e) rank += (int)((sS[e] == s) && (e < t));
        csr_eid[sOf[s] + rank] = t;                 // stable order within segment
        logA0[t] = logf(A0[s * NNODE + dst[t]] + 1e-8f);
    }
    if (t <= NNODE) csr_off[t] = sOf[t];
}

// ---------------------------------------------------------------------------
// fp32 -> split bf16 (hi + lo), grid-stride over float4s.
// ---------------------------------------------------------------------------
__global__ __launch_bounds__(256) void prep_split(const float* __restrict__ s,
    u16* __restrict__ h, u16* __restrict__ l, int n4)
{
    for (int i = blockIdx.x * 256 + threadIdx.x; i < n4; i += gridDim.x * 256) {
        float4 v = ((const float4*)s)[i];
        u16 h0 = f2bf(v.x), h1 = f2bf(v.y), h2 = f2bf(v.z), h3 = f2bf(v.w);
        ((ushort4*)h)[i] = make_ushort4(h0, h1, h2, h3);
        ((ushort4*)l)[i] = make_ushort4(f2bf(v.x - bf2f(h0)), f2bf(v.y - bf2f(h1)),
                                        f2bf(v.z - bf2f(h2)), f2bf(v.w - bf2f(h3)));
    }
}

// ---------------------------------------------------------------------------
// Split-bf16 MFMA GEMM. FULL: 3-pass (hh+hl+lh, fp32-grade); else 1-pass bf16.
// 128x128 tile, BK=32, 256 threads (4 waves). 1D grid, n-fastest pairing +
// bijective XCD swizzle (nwg=1024 % 8 == 0) for A-tile L2 reuse.
// ---------------------------------------------------------------------------
template<bool FULL, bool OUT_BF16>
__global__ __launch_bounds__(256) void gemm_bf16s(const u16* __restrict__ Ah,
    const u16* __restrict__ Al, const u16* __restrict__ Bh, const u16* __restrict__ Bl,
    void* __restrict__ Cout)
{
    __shared__ u16 sAh[4096], sBh[4096];                 // [128][32], linear
    __shared__ u16 sAl[FULL ? 4096 : 16], sBl[FULL ? 4096 : 16];
    const int t = threadIdx.x, lane = t & 63, wave = t >> 6;
    const int wm = wave >> 1, wn = wave & 1;
    const int bid = blockIdx.x;
    const int swz = (bid & 7) * 128 + (bid >> 3);        // XCD-contiguous
    const int m0 = (swz >> 1) * 128, n0 = (swz & 1) * 128;
    const int fr = lane & 15, kq = (lane >> 4) * 8;

    f32x4 acc[4][4];
    #pragma unroll
    for (int i = 0; i < 4; ++i)
        #pragma unroll
        for (int j = 0; j < 4; ++j) acc[i][j] = 0.f;

    for (int k0 = 0; k0 < D_; k0 += 32) {
        #pragma unroll
        for (int s = 0; s < 2; ++s) {
            const int cb = (s * 4 + wave) * 64;
            const int c  = cb + lane;
            const int row = c >> 2, ks = (c & 3) * 8;
            const size_t ga = (size_t)(m0 + row) * D_ + k0 + ks;
            const size_t gb = (size_t)(n0 + row) * D_ + k0 + ks;
            GLD16(Ah + ga, sAh + cb * 8);
            GLD16(Bh + gb, sBh + cb * 8);
            if (FULL) {
                GLD16(Al + ga, sAl + cb * 8);
                GLD16(Bl + gb, sBl + cb * 8);
            }
        }
        __syncthreads();

        s16x8 fah[4], fal[4];
        #pragma unroll
        for (int mi = 0; mi < 4; ++mi) {
            fah[mi] = *(const s16x8*)(sAh + (wm * 64 + mi * 16 + fr) * 32 + kq);
            if (FULL) fal[mi] = *(const s16x8*)(sAl + (wm * 64 + mi * 16 + fr) * 32 + kq);
        }
        #pragma unroll
        for (int ni = 0; ni < 4; ++ni) {
            s16x8 fbh = *(const s16x8*)(sBh + (wn * 64 + ni * 16 + fr) * 32 + kq);
            s16x8 fbl;
            if (FULL) fbl = *(const s16x8*)(sBl + (wn * 64 + ni * 16 + fr) * 32 + kq);
            #pragma unroll
            for (int mi = 0; mi < 4; ++mi) {
                acc[mi][ni] = __builtin_amdgcn_mfma_f32_16x16x32_bf16(fah[mi], fbh, acc[mi][ni], 0, 0, 0);
                if (FULL) {
                    acc[mi][ni] = __builtin_amdgcn_mfma_f32_16x16x32_bf16(fah[mi], fbl, acc[mi][ni], 0, 0, 0);
                    acc[mi][ni] = __builtin_amdgcn_mfma_f32_16x16x32_bf16(fal[mi], fbh, acc[mi][ni], 0, 0, 0);
                }
            }
        }
        __syncthreads();
    }

    const int fq = (lane >> 4) * 4;   // C/D: col = lane&15, row = (lane>>4)*4 + reg
    #pragma unroll
    for (int mi = 0; mi < 4; ++mi)
        #pragma unroll
        for (int ni = 0; ni < 4; ++ni)
            #pragma unroll
            for (int r = 0; r < 4; ++r) {
                size_t off = (size_t)(m0 + wm * 64 + mi * 16 + fq + r) * D_
                           + n0 + wn * 64 + ni * 16 + fr;
                if (OUT_BF16) ((u16*)Cout)[off] = f2bf(acc[mi][ni][r]);
                else          ((float*)Cout)[off] = acc[mi][ni][r];
            }
}

// ---------------------------------------------------------------------------
// Fused edge scores + segment softmax + aggregation, one block per (bt, head).
// Q fp32 16KB, V bf16 8KB, both XOR-swizzled (linear GLD16 dest + swizzled
// global source + swizzled read index) -> conflict-free LDS reads.
// ---------------------------------------------------------------------------
__global__ __launch_bounds__(256) void fused_edge_agg(
    const float* __restrict__ Xq, const u16* __restrict__ Xvb,
    const int* __restrict__ gsrc, const int* __restrict__ gdst,
    const float* __restrict__ a,
    const float* __restrict__ logA0, const int* __restrict__ csr_off,
    const int* __restrict__ csr_eid,
    u16* __restrict__ Yh, u16* __restrict__ Yl)
{
    __shared__ float sQ[NNODE * 64];      // 16 KB, 16B-chunk c ^= (row&15)
    __shared__ u16   sV[NNODE * 64];      // 8 KB,  16B-chunk c ^= (row&7)
    __shared__ float sE[NE];
    __shared__ float sLog[NE];
    __shared__ int   sPack[NE];           // (src<<8)|dst
    __shared__ int   sEid[NE];
    __shared__ float sDen[NNODE];
    __shared__ int   sOff[NNODE + 1];

    const int t = threadIdx.x;
    const int grp = t >> 4, lg = t & 15;      // 16 groups x 16 lanes
    const int bt = blockIdx.x >> 2, h = blockIdx.x & 3;

    // ---- stage Q/V via global_load_lds, source pre-swizzled (rule #21) ----
    const float* gq = Xq + (size_t)bt * NNODE * D_ + h * 64;
    {
        #pragma unroll
        for (int r = 0; r < 4; ++r) {
            int id = r * 256 + t;
            int row = id >> 4, c = id & 15;
            int csw = c ^ (row & 15);
            GLD16(gq + (size_t)row * D_ + csw * 4, (char*)sQ + id * 16);
        }
    }
    const u16* gv = Xvb + (size_t)bt * NNODE * D_ + h * 64;
    {
        #pragma unroll
        for (int r = 0; r < 2; ++r) {
            int id = r * 256 + t;
            int row = id >> 3, c = id & 7;
            int csw = c ^ (row & 7);
            GLD16(gv + (size_t)row * D_ + csw * 8, (char*)sV + id * 16);
        }
    }
    sPack[t]       = (gsrc[t] << 8)       | gdst[t];
    sPack[t + 256] = (gsrc[t + 256] << 8) | gdst[t + 256];
    sEid[t] = csr_eid[t]; sEid[t + 256] = csr_eid[t + 256];
    sLog[t] = logA0[t];   sLog[t + 256] = logA0[t + 256];
    if (t <= NNODE) sOff[t] = csr_off[t];
    const float4 areg = *(const float4*)&a[h * 64 + lg * 4];
    __syncthreads();   // drains global_load_lds (vmcnt) + lds writes

    // ---- edge scores: group handles 32 edges, 16 lanes x 4 dims ----
    for (int it = 0; it < 32; ++it) {
        int e = grp * 32 + it;
        int pk = sPack[e];
        int s_ = pk >> 8, d_ = pk & 255;
        float4 q = ((const float4*)sQ)[s_ * 16 + (lg ^ (s_ & 15))];
        float4 k = ((const float4*)sQ)[d_ * 16 + (lg ^ (d_ & 15))];
        float x0 = q.x + k.x, x1 = q.y + k.y, x2 = q.z + k.z, x3 = q.w + k.w;
        x0 = x0 > 0.f ? x0 : SLOPE * x0;
        x1 = x1 > 0.f ? x1 : SLOPE * x1;
        x2 = x2 > 0.f ? x2 : SLOPE * x2;
        x3 = x3 > 0.f ? x3 : SLOPE * x3;
        float p = x0 * areg.x + x1 * areg.y + x2 * areg.z + x3 * areg.w;
        p += __shfl_xor(p, 1);
        p += __shfl_xor(p, 2);
        p += __shfl_xor(p, 4);
        p += __shfl_xor(p, 8);
        if (lg == 0) sE[e] = p + sLog[e];
    }
    __syncthreads();

    // ---- segment softmax: 4 threads per node (quad in same wave) ----
    {
        int n = t >> 2, q = t & 3;
        int o0 = sOff[n], o1 = sOff[n + 1];
        float m = -INFINITY;
        for (int i = o0 + q; i < o1; i += 4) m = fmaxf(m, sE[sEid[i]]);
        m = fmaxf(m, __shfl_xor(m, 1));
        m = fmaxf(m, __shfl_xor(m, 2));
        float den = 0.f;
        for (int i = o0 + q; i < o1; i += 4) {
            int e = sEid[i];
            float w = __expf(sE[e] - m);
            den += w;
            sE[e] = w;                        // unnormalized weight
        }
        den += __shfl_xor(den, 1);
        den += __shfl_xor(den, 2);
        if (q == 0) sDen[n] = (o1 > o0) ? 1.f / den : 0.f;
    }
    __syncthreads();

    // ---- aggregate: group owns 4 nodes; scale by 1/den; split-bf16 output ----
    u16* yh = Yh + (size_t)bt * NNODE * D_ + h * 64;
    u16* yl = Yl + (size_t)bt * NNODE * D_ + h * 64;
    #pragma unroll
    for (int j = 0; j < 4; ++j) {
        int n = grp * 4 + j;
        int o0 = sOff[n], o1 = sOff[n + 1];
        float ax = 0.f, ay = 0.f, az = 0.f, aw = 0.f;
        for (int i = o0; i < o1; ++i) {
            int e = sEid[i];
            float w = sE[e];
            int d_ = sPack[e] & 255;
            ushort4 v = *(const ushort4*)&sV[d_ * 64 + (((lg >> 1) ^ (d_ & 7)) << 3)
                                             + ((lg & 1) << 2)];
            ax += w * bf2f(v.x); ay += w * bf2f(v.y);
            az += w * bf2f(v.z); aw += w * bf2f(v.w);
        }
        float inv = sDen[n];
        ax *= inv; ay *= inv; az *= inv; aw *= inv;
        u16 h0 = f2bf(ax), h1 = f2bf(ay), h2 = f2bf(az), h3 = f2bf(aw);
        *(ushort4*)&yh[(size_t)n * D_ + lg * 4] = make_ushort4(h0, h1, h2, h3);
        *(ushort4*)&yl[(size_t)n * D_ + lg * 4] =
            make_ushort4(f2bf(ax - bf2f(h0)), f2bf(ay - bf2f(h1)),
                         f2bf(az - bf2f(h2)), f2bf(aw - bf2f(h3)));
    }
}

// ---------------------------------------------------------------------------
extern "C" void kernel_launch(void* const* d_in, const int* in_sizes, int n_in,
                              void* d_out, int out_size, void* d_ws, size_t ws_size,
                              hipStream_t stream)
{
    const float* H     = (const float*)d_in[0];
    const float* W_lin = (const float*)d_in[1];
    const float* W_val = (const float*)d_in[2];
    const float* a     = (const float*)d_in[3];
    const float* W_out = (const float*)d_in[4];
    const float* A0    = (const float*)d_in[5];
    const int*   src   = (const int*)d_in[6];
    const int*   dst   = (const int*)d_in[7];

    const size_t nX = (size_t)BTN * D_;              // 16777216 elems
    // ws: Hh | Hl | Xq(fp32)  == 134217728 B exactly
    u16*   Hh = (u16*)d_ws;
    u16*   Hl = Hh + nX;
    float* Xq = (float*)(Hl + nX);
    u16*   Yh = Hh;                                  // alias: H dead after GEMM2
    u16*   Yl = Hl;
    u16*   Wouth = (u16*)Xq;                         // alias: Xq dead after fused
    u16*   Woutl = Wouth + D_ * D_;
    if (ws_size < (size_t)134217728) return;

    // d_out scratch until GEMM3: Xv bf16 [0,33.5MB) ; lists/W-splits at +40MB
    u16*   Xvb = (u16*)d_out;
    char*  sc2 = (char*)d_out + (size_t)40 * 1024 * 1024;
    float* logA0   = (float*)sc2;                    // 2 KB
    int*   csr_off = (int*)(sc2 + 4096);
    int*   csr_eid = (int*)(sc2 + 8192);
    u16*   Wlh = (u16*)(sc2 + 16384);                // 128 KB each
    u16*   Wll = Wlh + D_ * D_;
    u16*   Wvh = Wll + D_ * D_;
    u16*   Wvl = Wvh + D_ * D_;

    build_csr<<<1, 512, 0, stream>>>(src, dst, A0, csr_off, csr_eid, logA0);
    prep_split<<<4096, 256, 0, stream>>>(H, Hh, Hl, (int)(nX / 4));
    prep_split<<<64, 256, 0, stream>>>(W_lin, Wlh, Wll, D_ * D_ / 4);
    prep_split<<<64, 256, 0, stream>>>(W_val, Wvh, Wvl, D_ * D_ / 4);

    gemm_bf16s<true,  false><<<1024, 256, 0, stream>>>(Hh, Hl, Wlh, Wll, Xq);
    gemm_bf16s<false, true ><<<1024, 256, 0, stream>>>(Hh, Hl, Wvh, Wvl, Xvb);

    fused_edge_agg<<<4096, 256, 0, stream>>>(Xq, Xvb, src, dst, a, logA0,
                                             csr_off, csr_eid, Yh, Yl);

    prep_split<<<64, 256, 0, stream>>>(W_out, Wouth, Woutl, D_ * D_ / 4);
    gemm_bf16s<true,  false><<<1024, 256, 0, stream>>>(Yh, Yl, Wouth, Woutl, (float*)d_out);
}